// Round 1
// 167.312 us; speedup vs baseline: 1.0042x; 1.0042x over previous
//
#include <hip/hip_runtime.h>
#include <cstddef>

namespace {

constexpr int B=4, V=6, C=256, HWS=1024, S=6144, NH=4, HD=64, VC=1536;

typedef short short8  __attribute__((ext_vector_type(8)));
typedef short short4v __attribute__((ext_vector_type(4)));
typedef float f32x4   __attribute__((ext_vector_type(4)));

__device__ inline short f2bf(float f){
  union{float f; unsigned u;} v; v.f=f;
  unsigned r = v.u + 0x7fffu + ((v.u>>16)&1u);   // RNE
  return (short)(r>>16);
}
__device__ inline unsigned fbits(float f){
  union{float f; unsigned u;} v; v.f=f; return v.u;
}

// async global->LDS, 16B per lane; LDS dest = wave-uniform base, HW adds lane*16
typedef const __attribute__((address_space(1))) unsigned* gas_t;
typedef __attribute__((address_space(3))) unsigned* las_t;
__device__ inline void gll(const void* g, void* l){
  __builtin_amdgcn_global_load_lds((gas_t)g, (las_t)l, 16, 0, 0);
}

// ---------------------------------------------------------------------------
// 64x64 transpose-cast tile, register 4x4 micro-transpose (no LDS).
// ---------------------------------------------------------------------------
__device__ inline void tr_tile(const float* in, int inRow, short* out, int outRow,
                               int r0, int c0, int t){
  const int tx=t&15, ty=t>>4;
  float a[4][4];
  #pragma unroll
  for(int i=0;i<4;i++){
    const float4 f=*(const float4*)(in + (size_t)(r0+ty*4+i)*inRow + c0 + tx*4);
    a[i][0]=f.x; a[i][1]=f.y; a[i][2]=f.z; a[i][3]=f.w;
  }
  #pragma unroll
  for(int j=0;j<4;j++){
    short4v o4;
    #pragma unroll
    for(int i=0;i<4;i++) o4[i]=f2bf(a[i][j]);
    *(short4v*)(out + (size_t)(c0+tx*4+j)*outRow + r0+ty*4) = o4;
  }
}

// Combined prep: blocks 0..1535 transpose-cast x; 1536+ transpose-cast weights.
__global__ __launch_bounds__(256) void prep(const float* __restrict__ x,
                                            const float* __restrict__ Wq, const float* __restrict__ Wk,
                                            const float* __restrict__ Wv, const float* __restrict__ Wo,
                                            short* __restrict__ xb, short* __restrict__ WqT,
                                            short* __restrict__ WkT, short* __restrict__ WvT,
                                            short* __restrict__ WoT){
  const int blk=blockIdx.x;
  if(blk<1536){
    const int bx=blk&15, by=(blk>>4)&3, bv=blk>>6;
    tr_tile(x + (size_t)bv*C*HWS, HWS, xb + (size_t)bv*HWS*C, C, by*64, bx*64, threadIdx.x);
  } else {
    const int idx=blk-1536;
    const int tile=idx%96, z=idx/96;
    const float* in; short* out; int R;
    if(z==0){in=Wq; out=WqT; R=C;}
    else if(z==1){in=Wo; out=WoT; R=C;}
    else if(z==2){in=Wk; out=WkT; R=VC;}
    else         {in=Wv; out=WvT; R=VC;}
    const int tilesC=C/64, ntiles=(R/64)*tilesC;
    if(tile>=ntiles) return;
    tr_tile(in, C, out, R, (tile/tilesC)*64, (tile%tilesC)*64, threadIdx.x);
  }
}

// ---------------------------------------------------------------------------
// qo GEMM body, tile 128x64, BK=64, m97-style: gll staging, double-buffered
// LDS (2 x (A 16KB + B 8KB)), one barrier/iter, next-tile gll issued before
// compute. Tiles pitch-64 (gll order). MODE 0: bf16*QSCALE; MODE 1: fp32+res.
// ---------------------------------------------------------------------------
template<int MODE>
__device__ inline void qo_body(const short* __restrict__ A, const short* __restrict__ BT,
                               const float* __restrict__ bias, const float* __restrict__ xres,
                               void* __restrict__ outv, short* sh, int n0, int r0){
  const int t=threadIdx.x, lane=t&63, w=t>>6, quad=lane>>4, ln=lane&15;
  f32x4 acc[2][4];
  #pragma unroll
  for(int rt=0;rt<2;rt++)
    #pragma unroll
    for(int nt=0;nt<4;nt++) acc[rt][nt]=(f32x4)0.f;

  const int sr=w*8+(lane>>3), scc=(lane&7)*8;
  auto stage=[&](int it,int bufi){
    const int k0=it*64;
    short* dst = sh + bufi*12288;
    const short* Asrc = A + (size_t)r0*C + k0;
    #pragma unroll
    for(int cc=0; cc<4; cc++)
      gll(Asrc + (size_t)(sr+cc*32)*C + scc, dst + cc*2048 + w*512);
    const short* Bsrc = BT + (size_t)n0*C + k0;
    gll(Bsrc + (size_t)sr*C + scc,      dst + 8192 + w*512);
    gll(Bsrc + (size_t)(sr+32)*C + scc, dst + 8192 + 2048 + w*512);
  };

  stage(0,0);
  __syncthreads();
  for(int it=0; it<4; it++){
    if(it<3) stage(it+1,(it+1)&1);
    const short* As_=sh+(it&1)*12288;
    const short* Bs_=As_+8192;
    #pragma unroll
    for(int s=0;s<2;s++){
      const short8 af0=*(const short8*)&As_[(w*32+ln)*64    + s*32+quad*8];
      const short8 af1=*(const short8*)&As_[(w*32+16+ln)*64 + s*32+quad*8];
      #pragma unroll
      for(int nt=0;nt<4;nt++){
        const short8 bf=*(const short8*)&Bs_[(nt*16+ln)*64 + s*32+quad*8];
        acc[0][nt]=__builtin_amdgcn_mfma_f32_16x16x32_bf16(af0,bf,acc[0][nt],0,0,0);
        acc[1][nt]=__builtin_amdgcn_mfma_f32_16x16x32_bf16(af1,bf,acc[1][nt],0,0,0);
      }
    }
    __syncthreads();
  }

  constexpr float QSCALE = 0.18033688011112042f;  // 0.125/ln2: softmax via exp2
  float bcol[4];
  #pragma unroll
  for(int nt=0;nt<4;nt++) bcol[nt]=bias[n0+nt*16+ln];
  #pragma unroll
  for(int rt=0;rt<2;rt++)
    #pragma unroll
    for(int nt=0;nt<4;nt++)
      #pragma unroll
      for(int i=0;i<4;i++){
        const int row=r0+w*32+rt*16+quad*4+i, col=n0+nt*16+ln;
        const float vv=acc[rt][nt][i]+bcol[nt];
        if constexpr(MODE==0) ((short*)outv)[(size_t)row*C+col]=f2bf(vv*QSCALE);
        else ((float*)outv)[(size_t)row*C+col]=vv + xres[(size_t)row*C+col];
      }
}

// ---------------------------------------------------------------------------
// Combined projection kernel. Blocks 0..255: fused K+V proj (m97-style gll
// double-buffered staging of A/Bk/Bv) -> fragment-packed Kpack/Vpack.
// Blocks 256..1023: Q projection via qo_body.
// ---------------------------------------------------------------------------
__global__ __launch_bounds__(256) void proj(const short* __restrict__ xb,
                                            const short* __restrict__ WqT, const short* __restrict__ WkT,
                                            const short* __restrict__ WvT,
                                            const float* __restrict__ bq, const float* __restrict__ bk,
                                            const float* __restrict__ bv,
                                            short* __restrict__ qb, short* __restrict__ Kpack,
                                            short* __restrict__ Vpack){
  __shared__ __align__(16) short sh[24576];   // 48 KB: 2 bufs x 3 x 64x64
  const int blk=blockIdx.x;
  const int t=threadIdx.x, lane=t&63, w=t>>6, quad=lane>>4, ln=lane&15;

  if(blk>=256){
    const int qblk=blk-256;
    qo_body<0>(xb, WqT, bq, nullptr, qb, sh, (qblk&3)*64, (qblk>>2)*128);
    return;
  }

  // ---- kv path ----
  const int n0=(blk&3)*64, r0=(blk>>2)*64;
  const int b=r0>>10, hw0=r0&1023;
  const int h=n0>>6, bh=b*NH+h;

  f32x4 ak[4], av[4];
  #pragma unroll
  for(int nt=0;nt<4;nt++){ ak[nt]=(f32x4)0.f; av[nt]=(f32x4)0.f; }

  const int sr=w*8+(lane>>3), scc=(lane&7)*8;
  auto stageKV=[&](int it,int bufi){
    const int k0=it*64, v=k0>>8, c0=k0&255;
    short* dst = sh + bufi*12288;
    const short* As_src = xb + (size_t)((b*V+v)*HWS + hw0)*C + c0;
    gll(As_src + (size_t)sr*C + scc,       dst + w*512);
    gll(As_src + (size_t)(sr+32)*C + scc,  dst + 2048 + w*512);
    const short* Bk_src = WkT + (size_t)n0*VC + k0;
    gll(Bk_src + (size_t)sr*VC + scc,      dst + 4096 + w*512);
    gll(Bk_src + (size_t)(sr+32)*VC + scc, dst + 4096 + 2048 + w*512);
    const short* Bv_src = WvT + (size_t)n0*VC + k0;
    gll(Bv_src + (size_t)sr*VC + scc,      dst + 8192 + w*512);
    gll(Bv_src + (size_t)(sr+32)*VC + scc, dst + 8192 + 2048 + w*512);
  };

  stageKV(0,0);
  __syncthreads();
  for(int it=0; it<24; it++){
    if(it<23) stageKV(it+1,(it+1)&1);
    const short* As_=sh+(it&1)*12288;
    const short* Bk_=As_+4096;
    const short* Bv_=As_+8192;
    #pragma unroll
    for(int s=0;s<2;s++){
      const short8 af=*(const short8*)&As_[(w*16+ln)*64 + s*32+quad*8];
      #pragma unroll
      for(int nt=0;nt<4;nt++){
        const short8 kf=*(const short8*)&Bk_[(nt*16+ln)*64 + s*32+quad*8];
        const short8 vf=*(const short8*)&Bv_[(nt*16+ln)*64 + s*32+quad*8];
        ak[nt]=__builtin_amdgcn_mfma_f32_16x16x32_bf16(af,kf,ak[nt],0,0,0);
        av[nt]=__builtin_amdgcn_mfma_f32_16x16x32_bf16(af,vf,av[nt],0,0,0);
      }
    }
    __syncthreads();
  }

  float bkc[4], bvc[4];
  #pragma unroll
  for(int nt=0;nt<4;nt++){ bkc[nt]=bk[n0+nt*16+ln]; bvc[nt]=bv[n0+nt*16+ln]; }

  // V: C-layout (key=quad*4+i, dim=nt*16+ln) IS the PV A-frag mapping.
  {
    short* vq = Vpack + ((size_t)(bh*64 + (hw0>>4) + w))*1024;
    #pragma unroll
    for(int nt=0;nt<4;nt++){
      short4v vp;
      #pragma unroll
      for(int i=0;i<4;i++) vp[i]=f2bf(av[nt][i]+bvc[nt]);
      *(short4v*)(vq + nt*256 + lane*4) = vp;
    }
  }

  // K: transpose C-layout -> A-frag order via LDS (reuse sh, pitch 72)
  __syncthreads();
  #pragma unroll
  for(int nt=0;nt<4;nt++)
    #pragma unroll
    for(int i=0;i<4;i++)
      sh[(w*16+quad*4+i)*72 + nt*16+ln] = f2bf(ak[nt][i]+bkc[nt]);
  __syncthreads();
  {
    short* kp = Kpack + ((size_t)(bh*64 + (hw0>>4) + w))*1024;
    #pragma unroll
    for(int half=0; half<2; half++){
      const short8 f = *(short8*)&sh[(w*16+ln)*72 + half*32 + quad*8];
      *(short8*)(kp + half*512 + lane*8) = f;
    }
  }
}

// ---------------------------------------------------------------------------
// MFMA attention: LDS-staged fragment-packed K/V, 512 threads, 128 q-rows/blk.
// R9: 3-buffer circular pipeline, counted vmcnt (never drained to 0 in the
// main loop) + single raw s_barrier per tile (T3/T4), s_setprio around MFMA
// clusters (T5). Per wave per tile: exactly 2 glls (K,V slice) -> vmcnt(2)
// leaves next tile's loads in flight across the barrier.
// ---------------------------------------------------------------------------
__global__ __launch_bounds__(512,4) void attn_k(const short* __restrict__ q, const short* __restrict__ Kpack,
                                                const short* __restrict__ Vpack, short* __restrict__ ao){
  __shared__ __align__(16) char smem[50176];
  short* KV   = (short*)smem;                 // 3 bufs x 8192 shorts (16 KB)
  float* obuf = (float*)smem;                 // overlay after loop: 64 x pitch 132
  float* lbuf = (float*)(smem + 49152);

  const int blk=blockIdx.x;
  const int bh=(blk&7)*2 + ((blk>>3)&1);
  const int qt=blk>>4;
  const int b=bh>>2, h=bh&3;
  const int s0=qt*128;
  const int t=threadIdx.x, lane=t&63, w=t>>6, quad=lane>>4, ln=lane&15;
  const int wq=w&3, wk=w>>2;

  short8 qf[2][2];
  #pragma unroll
  for(int ntl=0;ntl<2;ntl++)
    #pragma unroll
    for(int s=0;s<2;s++)
      qf[ntl][s]=*(const short8*)&q[(size_t)(b*S+s0+wq*32+ntl*16+ln)*C + h*HD + s*32+quad*8];

  f32x4 o[4][2];
  #pragma unroll
  for(int dt=0;dt<4;dt++)
    #pragma unroll
    for(int ntl=0;ntl<2;ntl++) o[dt][ntl]=(f32x4)0.f;
  f32x4 l4[2];
  l4[0]=(f32x4)0.f; l4[1]=(f32x4)0.f;

  const short* Kt = Kpack + (size_t)bh*65536;
  const short* Vt = Vpack + (size_t)bh*65536;
  const f32x4 z4=(f32x4)0.f;
  const int rb = s0 + wq*32;

  // prologue: stage tiles 0 and 1 (per wave: K0,V0,K1,V1 in order)
  gll(Kt + w*512 + lane*8,        KV + w*512);
  gll(Vt + w*512 + lane*8,        KV + 4096 + w*512);
  gll(Kt + 4096 + w*512 + lane*8, KV + 8192 + w*512);
  gll(Vt + 4096 + w*512 + lane*8, KV + 8192 + 4096 + w*512);

  int cb = 0;   // buffer holding tile TI
  int pb = 2;   // buffer for tile TI+2 staging
  #pragma unroll 1
  for(int TI=0; TI<16; TI++){
    // Counted wait: each wave's own stage(TI) glls retired (vmcnt(2) leaves
    // stage(TI+1) in flight); barrier makes that true across all 8 waves.
    // lgkmcnt(0): paranoia — all prior ds_reads already consumed by MFMAs.
    if(TI<15) asm volatile("s_waitcnt vmcnt(2) lgkmcnt(0)\n\ts_barrier" ::: "memory");
    else      asm volatile("s_waitcnt vmcnt(0) lgkmcnt(0)\n\ts_barrier" ::: "memory");

    // stage TI+2 into buf[(TI+2)%3] (= buffer whose reads finished at TI-1,
    // proven by the barrier above)
    if(TI<14){
      gll(Kt + (size_t)(TI+2)*4096 + w*512 + lane*8, KV + pb*8192 + w*512);
      gll(Vt + (size_t)(TI+2)*4096 + w*512 + lane*8, KV + pb*8192 + 4096 + w*512);
    }

    const short* Kb = KV + cb*8192;
    const short* Vb = Kb + 4096;

    const short8 kf00=*(const short8*)&Kb[wk*2048 + lane*8];
    const short8 kf01=*(const short8*)&Kb[wk*2048 + 512 + lane*8];
    const short8 kf10=*(const short8*)&Kb[wk*2048 + 1024 + lane*8];
    const short8 kf11=*(const short8*)&Kb[wk*2048 + 1536 + lane*8];

    f32x4 sa[2][2];
    __builtin_amdgcn_s_setprio(1);
    #pragma unroll
    for(int ntl=0;ntl<2;ntl++){
      sa[0][ntl]=__builtin_amdgcn_mfma_f32_16x16x32_bf16(kf00,qf[ntl][0],z4,0,0,0);
      sa[0][ntl]=__builtin_amdgcn_mfma_f32_16x16x32_bf16(kf01,qf[ntl][1],sa[0][ntl],0,0,0);
      sa[1][ntl]=__builtin_amdgcn_mfma_f32_16x16x32_bf16(kf10,qf[ntl][0],z4,0,0,0);
      sa[1][ntl]=__builtin_amdgcn_mfma_f32_16x16x32_bf16(kf11,qf[ntl][1],sa[1][ntl],0,0,0);
    }
    __builtin_amdgcn_s_setprio(0);

    short4v vf[2][4];
    #pragma unroll
    for(int kt=0;kt<2;kt++)
      #pragma unroll
      for(int dt=0;dt<4;dt++)
        vf[kt][dt]=*(const short4v*)&Vb[wk*2048 + kt*1024 + dt*256 + lane*4];

    const int kmin=TI*64 + wk*32;
    if(kmin+31 >= rb-3 && kmin <= rb+34){
      #pragma unroll
      for(int kt=0;kt<2;kt++)
        #pragma unroll
        for(int ntl=0;ntl<2;ntl++){
          const int ig=rb+ntl*16+ln;
          #pragma unroll
          for(int i=0;i<4;i++){
            const int jg=kmin+kt*16+quad*4+i;
            if((unsigned)(jg-ig+3)<=6u) sa[kt][ntl][i]=-100.f;
          }
        }
    }

    short4v pt[2][2];
    #pragma unroll
    for(int kt=0;kt<2;kt++)
      #pragma unroll
      for(int ntl=0;ntl<2;ntl++){
        f32x4 pv;
        #pragma unroll
        for(int i=0;i<4;i++) pv[i]=__builtin_amdgcn_exp2f(sa[kt][ntl][i]);
        l4[ntl]+=pv;
        union{ short4v s; unsigned u[2]; } P;
        P.u[0]=__builtin_amdgcn_perm(fbits(pv[1]), fbits(pv[0]), 0x07060302u);
        P.u[1]=__builtin_amdgcn_perm(fbits(pv[3]), fbits(pv[2]), 0x07060302u);
        pt[kt][ntl]=P.s;
      }

    __builtin_amdgcn_s_setprio(1);
    #pragma unroll
    for(int kt=0;kt<2;kt++)
      #pragma unroll
      for(int dt=0;dt<4;dt++)
        #pragma unroll
        for(int ntl=0;ntl<2;ntl++)
          o[dt][ntl]=__builtin_amdgcn_mfma_f32_16x16x16bf16_1k(vf[kt][dt],pt[kt][ntl],o[dt][ntl],0,0,0);
    __builtin_amdgcn_s_setprio(0);

    cb = (cb==2)?0:cb+1;
    pb = (pb==2)?0:pb+1;
  }

  __syncthreads();   // all waves done reading KV before obuf overlay

  float l[2];
  #pragma unroll
  for(int ntl=0;ntl<2;ntl++){
    l[ntl]=l4[ntl][0]+l4[ntl][1]+l4[ntl][2]+l4[ntl][3];
    l[ntl]+=__shfl_xor(l[ntl],16);
    l[ntl]+=__shfl_xor(l[ntl],32);
  }
  if(quad==0){
    lbuf[w*32+ln]    = l[0];
    lbuf[w*32+16+ln] = l[1];
  }
  if(wk==0){
    #pragma unroll
    for(int dt=0;dt<4;dt++)
      #pragma unroll
      for(int ntl=0;ntl<2;ntl++)
        #pragma unroll
        for(int i=0;i<4;i++)
          obuf[(dt*16+quad*4+i)*132 + wq*32+ntl*16+ln] = o[dt][ntl][i];
  }
  __syncthreads();
  if(wk==1){
    #pragma unroll
    for(int dt=0;dt<4;dt++)
      #pragma unroll
      for(int ntl=0;ntl<2;ntl++)
        #pragma unroll
        for(int i=0;i<4;i++)
          obuf[(dt*16+quad*4+i)*132 + wq*32+ntl*16+ln] += o[dt][ntl][i];
  }
  __syncthreads();

  {
    const int row=t>>2, dg=t&3;
    const float linv=1.0f/(lbuf[(row>>5)*32 + (row&31)] + lbuf[(4+(row>>5))*32 + (row&31)]);
    short tmp[16];
    #pragma unroll
    for(int j=0;j<16;j++) tmp[j]=f2bf(obuf[(dg*16+j)*132+row]*linv);
    short* op = ao + (size_t)(b*S+s0+row)*C + h*HD + dg*16;
    *(short8*)op     = *(short8*)&tmp[0];
    *(short8*)(op+8) = *(short8*)&tmp[8];
  }
}

// O-projection + residual (MODE 1 wrapper)
__global__ __launch_bounds__(256) void o_gemm(const short* __restrict__ A, const short* __restrict__ BT,
                                              const float* __restrict__ bias, const float* __restrict__ xres,
                                              float* __restrict__ out){
  __shared__ __align__(16) short sh[24576];
  qo_body<1>(A, BT, bias, xres, out, sh, (int)(blockIdx.x&3)*64, (int)(blockIdx.x>>2)*128);
}

}  // namespace

extern "C" void kernel_launch(void* const* d_in, const int* in_sizes, int n_in,
                              void* d_out, int out_size, void* d_ws, size_t ws_size,
                              hipStream_t stream) {
  const float* x  = (const float*)d_in[0];
  const float* Wq = (const float*)d_in[1];
  const float* bq = (const float*)d_in[2];
  const float* Wk = (const float*)d_in[3];
  const float* bk = (const float*)d_in[4];
  const float* Wv = (const float*)d_in[5];
  const float* bv = (const float*)d_in[6];
  const float* Wo = (const float*)d_in[7];
  const float* bo = (const float*)d_in[8];
  float* out = (float*)d_out;

  char* p = (char*)d_ws;
  const size_t szBS=(size_t)B*S*C*2, szK=(size_t)B*HWS*C*2;
  short* xb   =(short*)p; p+=szBS;
  short* qb   =(short*)p; p+=szBS;
  short* aob  =(short*)p; p+=szBS;
  short* Kpack=(short*)p; p+=szK;
  short* Vpack=(short*)p; p+=szK;
  short* WqT=(short*)p; p+=(size_t)C*C*2;
  short* WoT=(short*)p; p+=(size_t)C*C*2;
  short* WkT=(short*)p; p+=(size_t)C*VC*2;
  short* WvT=(short*)p; p+=(size_t)C*VC*2;

  prep<<<dim3(1920), 256, 0, stream>>>(x, Wq,Wk,Wv,Wo, xb, WqT,WkT,WvT,WoT);
  proj<<<dim3(1024), 256, 0, stream>>>(xb, WqT,WkT,WvT, bq,bk,bv, qb, Kpack, Vpack);
  attn_k<<<dim3(B*NH*(S/128)), 512, 0, stream>>>(qb, Kpack, Vpack, aob);
  o_gemm<<<dim3(4*((B*S)/128)), 256, 0, stream>>>(aob, WoT, bo, x, out);
}